// Round 1
// baseline (1585.115 us; speedup 1.0000x reference)
//
#include <hip/hip_runtime.h>
#include <hip/hip_fp16.h>

// GPTQ int4 dequant + GEMM, fused.
//   x        [4,2048,4096] fp32  -> A [M=8192][K=4096], cast to fp16 (RTE, matches ref)
//   qweight  [512,11008] int32   -> W[k][n]: nibble j of qweight[k/8][n], k = 8*(k/8)+j
//   qzeros   [32,1376]  int32    -> z[g][n]: nibble (n%8) of qzeros[g][n/8]
//   scales   [32,11008] -- fp16 in the reference; harness materializes as fp32. Read as float.
//   dequant  fp16( (w - z[g]) * s[g] ),  g = k/128
//   out      [M][N=11008] fp32, fp32 accumulation via MFMA
//
// R2: packed-fp16 bit-trick dequant (VALU was the bottleneck: 62% VALUBusy vs 29% MfmaUtil).
//   nibble->fp16 via (raw>>4p & 0x000F000F) | 0x64006400  == {1024+n_p, 1024+n_{p+4}},
//   then v_pk (sub, mul): (w-z) exact in fp16 (ints <=15 at ulp=1), fp16 mul = single RTE
//   round of the exact product == ref's fp32-product -> RTE-fp16. Bit-exact to reference.
//   k within each 8-group is stored interleaved {0,4,1,5,2,6,3,7}; A is staged in the SAME
//   order (dot product is permutation-invariant), so MFMA results are unchanged.
//
// Structure: 128x128 tile, BK=64, 4 waves in 2x2, wave tile 64x64 = 4x4 frags of
// mfma_f32_16x16x32_f16. LDS As[m][k], Bs[n][k], k-contiguous, LDK=72 halves
// (144 B row stride = 36 banks -> 2-way aliasing only, free per m136).

#define M_TOT 8192
#define N_TOT 11008
#define K_TOT 4096

#define BM 128
#define BN 128
#define BK 64
#define LDK 72  // padded K stride in halves (+8 -> 16B pad)

typedef _Float16 half2v __attribute__((ext_vector_type(2)));
typedef _Float16 half8 __attribute__((ext_vector_type(8)));
typedef float float4v __attribute__((ext_vector_type(4)));

__global__ __launch_bounds__(256) void gptq_fused_gemm(
    const float* __restrict__ x,
    const int* __restrict__ qw,
    const unsigned* __restrict__ qz,
    const float* __restrict__ sc,   // fp32 buffer (harness upcasts fp16 inputs)
    float* __restrict__ out)
{
    __shared__ _Float16 As[BM * LDK];
    __shared__ _Float16 Bs[BN * LDK];

    const int tid = threadIdx.x;
    const int bn = blockIdx.x;            // 0..85  (N/128)
    const int bm = blockIdx.y;            // 0..63  (M/128)
    const int m0 = bm * BM;
    const int n0 = bn * BN;

    const int wave = tid >> 6;
    const int lane = tid & 63;
    const int wr = wave >> 1;             // wave row (m), 0..1
    const int wc = wave & 1;              // wave col (n), 0..1
    const int l16 = lane & 15;
    const int quad = lane >> 4;

    // A staging: thread -> 8-k unit a_k8 of rows a_m + 32*i (permuted-k pack needs all 8 k local)
    const int a_k8 = tid & 7;             // which 8-k group within BK (k = 8*a_k8)
    const int a_m  = tid >> 3;            // 0..31, covers rows a_m + 32*i
    // B staging: thread -> column b_n, qweight rows b_rr + 2*i
    const int b_n  = tid & 127;
    const int b_rr = tid >> 7;
    const int ncol = n0 + b_n;

    float4v acc[4][4] = {};

    for (int k0 = 0; k0 < K_TOT; k0 += BK) {
        __syncthreads();  // protect LDS from previous iteration's reads

        // ---- stage A: x[m0..+128][k0..+64] fp32 -> As[m][k-permuted] fp16 (RTE)
        {
            const float* src = x + (size_t)(m0 + a_m) * K_TOT + k0 + a_k8 * 8;
            #pragma unroll
            for (int i = 0; i < 4; ++i) {
                const float* p = src + (size_t)(i * 32) * K_TOT;
                float4v v0 = *(const float4v*)p;        // k 0..3 of the 8-group
                float4v v1 = *(const float4v*)(p + 4);  // k 4..7
                half8 h;                                 // order {0,4,1,5,2,6,3,7}
                h[0] = (_Float16)v0[0]; h[1] = (_Float16)v1[0];
                h[2] = (_Float16)v0[1]; h[3] = (_Float16)v1[1];
                h[4] = (_Float16)v0[2]; h[5] = (_Float16)v1[2];
                h[6] = (_Float16)v0[3]; h[7] = (_Float16)v1[3];
                *(half8*)&As[(a_m + 32 * i) * LDK + a_k8 * 8] = h;  // ds_write_b128
            }
        }

        // ---- stage B: dequant qweight[k0/8 .. +8][n0..+128] -> Bs[n][k-permuted] fp16
        {
            const int g = k0 >> 7;  // group = k0/128; BK=64 divides group size
            const _Float16 s_h = (_Float16)sc[g * N_TOT + ncol];
            half2v sp; sp[0] = s_h; sp[1] = s_h;
            const unsigned zraw = qz[g * (N_TOT / 8) + (ncol >> 3)];
            const unsigned zn = (zraw >> ((ncol & 7) * 4)) & 15u;
            const half2v zp = __builtin_bit_cast(half2v, 0x64006400u | zn | (zn << 16));
            const int krow0 = k0 >> 3;
            #pragma unroll
            for (int i = 0; i < 4; ++i) {
                const int rr = b_rr + 2 * i;  // 0..7
                const unsigned raw = (unsigned)qw[(size_t)(krow0 + rr) * N_TOT + ncol];
                half8 w;
                #pragma unroll
                for (int p = 0; p < 4; ++p) {
                    // {1024+n_p, 1024+n_{p+4}} as packed fp16 -- one v_and_or_b32 (+shift)
                    const unsigned bits = ((raw >> (4 * p)) & 0x000F000Fu) | 0x64006400u;
                    half2v d = (__builtin_bit_cast(half2v, bits) - zp) * sp;  // v_pk ops, exact
                    w[2 * p]     = d[0];
                    w[2 * p + 1] = d[1];
                }
                *(half8*)&Bs[b_n * LDK + rr * 8] = w;  // ds_write_b128, 16B aligned
            }
        }

        __syncthreads();

        // ---- compute: 2 x (4 A-frags + 4 B-frags + 16 MFMA)
        #pragma unroll
        for (int kk = 0; kk < 2; ++kk) {
            half8 af[4], bf[4];
            #pragma unroll
            for (int i = 0; i < 4; ++i)  // A[m=l16][k-perm group quad]
                af[i] = *(const half8*)&As[(wr * 64 + i * 16 + l16) * LDK + kk * 32 + quad * 8];
            #pragma unroll
            for (int j = 0; j < 4; ++j)  // B[k-perm group quad][n=l16]
                bf[j] = *(const half8*)&Bs[(wc * 64 + j * 16 + l16) * LDK + kk * 32 + quad * 8];
            #pragma unroll
            for (int i = 0; i < 4; ++i)
                #pragma unroll
                for (int j = 0; j < 4; ++j)
                    acc[i][j] = __builtin_amdgcn_mfma_f32_16x16x32_f16(af[i], bf[j], acc[i][j], 0, 0, 0);
        }
    }

    // ---- epilogue: C/D layout col = lane&15 (n), row = quad*4 + reg (m)
    float* o = out + (size_t)(m0 + wr * 64) * N_TOT + (n0 + wc * 64);
    #pragma unroll
    for (int i = 0; i < 4; ++i)
        #pragma unroll
        for (int j = 0; j < 4; ++j)
            #pragma unroll
            for (int r = 0; r < 4; ++r)
                o[(size_t)(i * 16 + quad * 4 + r) * N_TOT + (j * 16 + l16)] = acc[i][j][r];
}

extern "C" void kernel_launch(void* const* d_in, const int* in_sizes, int n_in,
                              void* d_out, int out_size, void* d_ws, size_t ws_size,
                              hipStream_t stream) {
    const float* x = (const float*)d_in[0];
    const int* qw = (const int*)d_in[1];
    const unsigned* qz = (const unsigned*)d_in[2];
    const float* sc = (const float*)d_in[3];
    float* out = (float*)d_out;

    dim3 grid(N_TOT / BN, M_TOT / BM, 1);  // (86, 64)
    gptq_fused_gemm<<<grid, dim3(256, 1, 1), 0, stream>>>(x, qw, qz, sc, out);
}